// Round 9
// baseline (91.099 us; speedup 1.0000x reference)
//
#include <hip/hip_runtime.h>
#include <math.h>
#include <stdint.h>

#define INF_F 1.0e12f
#define NB 8
#define HW 512
#define PLANE (HW*HW)          // 262144
#define NPIX (NB*PLANE)        // 2097152
#define TW 32                  // tile width  (x)
#define TH 64                  // tile height (y)
#define GX (HW/TW)             // 16
#define GY (HW/TH)             // 8
#define NBLK (GX*GY*NB)        // 1024 blocks
#define YH 3                   // vertical halo (scan depth)
#define WROWS (TH + 2*YH)      // 70 window rows

// -------- fully fused: bit-mask 2D EDT (both masks) + hd + dice + CE --------
// grid (16,8,8): 32x64 tile per block, 256 threads, 8 consecutive rows/thread.
// 48-bit row words (x-halo 8), y-halo 3. Branch-free bounded scan |dy|<=3;
// exact when m<=16 (side exits >= 81, unscanned rows >= 16). Rare fallback is
// an INLINE cold tail (no function call -> clean register allocation).
__global__ __launch_bounds__(256) void fused_loss(
    const float* __restrict__ outputs, const int* __restrict__ labels,
    float* __restrict__ partials)
{
  __shared__ uint64_t W[2][WROWS];   // bit t = window col t (x = x0-8+t)
  __shared__ float wredf[4][5];
  const int tid = threadIdx.x;
  const int wave = tid >> 6, lane = tid & 63;
  const int x0 = blockIdx.x * TW, y0 = blockIdx.y * TH, b = blockIdx.z;
  const int base1 = (b*2 + 1)*PLANE;

  // ---- prefetch epilogue operands first (overlap staging + barrier) ----
  const int lx = tid & 31, rg = tid >> 5;    // 8 row-groups of 8 rows
  const int x = x0 + lx;
  const int ybase = y0 + rg*8;
  float p1v[8], p0v[8], labf[8];
#pragma unroll
  for (int k = 0; k < 8; ++k) {
    const int off = base1 + (ybase + k)*HW + x;
    p1v[k]  = outputs[off];
    p0v[k]  = outputs[off - PLANE];
    labf[k] = (labels[off] > 0) ? 1.0f : 0.0f;
  }

  // ---- stage: 2 masks x 70 rows x 4 ushort chunks (ch 3 = zero pad) ----
  for (int idx = tid; idx < 2*WROWS*4; idx += 256) {
    const int z   = idx / (WROWS*4);
    const int rem = idx - z*(WROWS*4);
    const int row = rem >> 2, ch = rem & 3;
    const int yy = y0 - YH + row;
    const int xs = x0 - 8 + ch*16;
    uint32_t bits = 0;
    if (ch < 3 && yy >= 0 && yy < HW) {
      const int rb = base1 + yy*HW;
      if (xs >= 0 && xs + 16 <= HW) {
        if (z == 0) {
          const int4* p = (const int4*)(labels + rb + xs);
          const int4 a = p[0], c = p[1], d = p[2], e = p[3];
          const int v[16] = {a.x,a.y,a.z,a.w, c.x,c.y,c.z,c.w,
                             d.x,d.y,d.z,d.w, e.x,e.y,e.z,e.w};
#pragma unroll
          for (int t = 0; t < 16; ++t) if (v[t] <= 0) bits |= (1u << t);
        } else {
          const float4* p = (const float4*)(outputs + rb + xs);
          const float4 a = p[0], c = p[1], d = p[2], e = p[3];
          const float v[16] = {a.x,a.y,a.z,a.w, c.x,c.y,c.z,c.w,
                               d.x,d.y,d.z,d.w, e.x,e.y,e.z,e.w};
#pragma unroll
          for (int t = 0; t < 16; ++t) if (!(v[t] > 0.5f)) bits |= (1u << t);
        }
      } else {
        for (int t = 0; t < 16; ++t) {
          const int xx = xs + t;
          if (xx < 0 || xx >= HW) continue;
          const bool bg = (z == 0) ? (labels[rb + xx] <= 0)
                                   : !(outputs[rb + xx] > 0.5f);
          if (bg) bits |= (1u << t);
        }
      }
    }
    ((unsigned short*)W)[idx] = (unsigned short)bits;  // LE overlay into words
  }
  __syncthreads();

  // ---- branch-free per-pixel EDT: 8 consecutive rows per thread ----
  const int px = 8 + lx, sh = 63 - px;
  const int ry0 = YH + rg*8;                 // window row of first pixel
  float d2sum[8];
  uint32_t fbits = 0;                        // fallback flags: bit z*8+k
#pragma unroll
  for (int k = 0; k < 8; ++k) d2sum[k] = 0.0f;
#pragma unroll
  for (int z = 0; z < 2; ++z) {
    int rd2[14];                             // rows ry0-3 .. ry0+10
#pragma unroll
    for (int j = 0; j < 14; ++j) {
      const uint64_t w = W[z][ry0 - YH + j];
      const int dL = __builtin_clzll((w << sh) | 1ull);          // empty -> 63
      const int dR = __builtin_ctzll((w >> px) | (1ull << 63));  // empty -> 63
      const int d = min(dL, dR);
      rd2[j] = d*d;
    }
#pragma unroll
    for (int k = 0; k < 8; ++k) {
      int m = rd2[k+3];
      m = min(m, 1 + min(rd2[k+2], rd2[k+4]));
      m = min(m, 4 + min(rd2[k+1], rd2[k+5]));
      m = min(m, 9 + min(rd2[k+0], rd2[k+6]));
      if (__builtin_expect(m > 16, 0)) {     // certificate failed (never)
        fbits |= (1u << (z*8 + k));
      } else {
        d2sum[k] += (float)m;
      }
    }
  }

  // ---- cold inline fallback: exact brute-force for flagged pixels ----
  if (__builtin_expect(fbits != 0, 0)) {
    for (int z = 0; z < 2; ++z) {
      for (int k = 0; k < 8; ++k) {
        if (!(fbits & (1u << (z*8 + k)))) continue;
        const int y = ybase + k;
        int mBest = 0x7fffffff;
        for (int yy = 0; yy < HW; ++yy) {
          const int dy = yy - y, a2 = dy*dy;
          if (a2 >= mBest) continue;
          const int rb = base1 + yy*HW;
          for (int xx = 0; xx < HW; ++xx) {
            const bool bg = (z == 0) ? (labels[rb + xx] <= 0)
                                     : !(outputs[rb + xx] > 0.5f);
            if (bg) {
              const int dx = xx - x, c2 = a2 + dx*dx;
              if (c2 < mBest) mBest = c2;
            }
          }
        }
        d2sum[k] += (mBest == 0x7fffffff) ? INF_F : (float)mBest;
      }
    }
  }

  // ---- fused hd / dice / CE (fp32 partials over 8 px) ----
  float s0 = 0, s1 = 0, s2 = 0, s3 = 0, s4 = 0;
#pragma unroll
  for (int k = 0; k < 8; ++k) {
    const float p1  = p1v[k];
    const float p0f = p0v[k];
    const float lf  = labf[k];
    const float dl = p1 - lf;
    s0 = fmaf(dl*dl, d2sum[k], s0);
    s1 = fmaf(p1, lf, s1);
    s2 = fmaf(p1, p1, s2);
    s3 += lf;
    const float mm  = fmaxf(p0f, p1);
    const float lse = mm + __logf(1.0f + __expf(fminf(p0f, p1) - mm));
    s4 += ((lf > 0.5f) ? p1 : p0f) - lse;
  }

  for (int off = 32; off > 0; off >>= 1) {
    s0 += __shfl_down(s0, off, 64);
    s1 += __shfl_down(s1, off, 64);
    s2 += __shfl_down(s2, off, 64);
    s3 += __shfl_down(s3, off, 64);
    s4 += __shfl_down(s4, off, 64);
  }
  if (lane == 0) {
    wredf[wave][0] = s0; wredf[wave][1] = s1; wredf[wave][2] = s2;
    wredf[wave][3] = s3; wredf[wave][4] = s4;
  }
  __syncthreads();
  if (tid < 5) {
    const int bid = (blockIdx.z*GY + blockIdx.y)*GX + blockIdx.x;
    partials[tid*NBLK + bid] =
        wredf[0][tid] + wredf[1][tid] + wredf[2][tid] + wredf[3][tid];
  }
}

// ---------------- Finalize: reduce 1024 block-partials, compute loss --------
__global__ __launch_bounds__(256) void finalize(
    const float* __restrict__ partials, float* __restrict__ out)
{
  __shared__ double wred[4][5];
  const int tid = threadIdx.x;
  double s[5] = {0, 0, 0, 0, 0};
  for (int i = tid; i < NBLK; i += 256) {
#pragma unroll
    for (int q = 0; q < 5; ++q) s[q] += (double)partials[q*NBLK + i];
  }
  for (int off = 32; off > 0; off >>= 1) {
#pragma unroll
    for (int q = 0; q < 5; ++q) s[q] += __shfl_down(s[q], off, 64);
  }
  const int w = tid >> 6;
  if ((tid & 63) == 0) {
#pragma unroll
    for (int q = 0; q < 5; ++q) wred[w][q] = s[q];
  }
  __syncthreads();
  if (tid == 0) {
#pragma unroll
    for (int q = 0; q < 5; ++q) s[q] = wred[0][q] + wred[1][q] + wred[2][q] + wred[3][q];
    const double N = (double)NPIX;
    const double hd   = s[0] / N;
    const double ce   = -(s[4] / N);
    const double dice = 1.0 - (2.0*s[1] + 1e-6) / (s[2] + s[3] + 1e-6);
    out[0] = (float)(ce + dice + 0.5 * hd);   // LAM=1, 1-ALPHA=0.5
  }
}

extern "C" void kernel_launch(void* const* d_in, const int* in_sizes, int n_in,
                              void* d_out, int out_size, void* d_ws, size_t ws_size,
                              hipStream_t stream)
{
  const float* outputs = (const float*)d_in[0];
  const int*   labels  = (const int*)d_in[1];
  float* partials = (float*)d_ws;   // [5][NBLK] floats = 20 KB

  fused_loss<<<dim3(GX, GY, NB), 256, 0, stream>>>(outputs, labels, partials);
  finalize<<<1, 256, 0, stream>>>(partials, (float*)d_out);
}

// Round 10
// 89.762 us; speedup vs baseline: 1.0149x; 1.0149x over previous
//
#include <hip/hip_runtime.h>
#include <math.h>
#include <stdint.h>

#define INF_F 1.0e12f
#define NB 8
#define HW 512
#define PLANE (HW*HW)          // 262144
#define NPIX (NB*PLANE)        // 2097152
#define TW 32                  // tile width  (x)
#define TH 64                  // tile height (y)
#define GX (HW/TW)             // 16
#define GY (HW/TH)             // 8
#define NBLK (GX*GY*NB)        // 1024 blocks
#define YH 3                   // vertical halo (scan depth)
#define WROWS (TH + 2*YH)      // 70 window rows

// -------- fully fused: bit-mask 2D EDT (both masks) + hd + dice + CE --------
// grid (16,8,8): 32x64 tile per block, 256 threads, 8 consecutive rows/thread.
// 48-bit row words (x-halo 8), y-halo 3. Branch-free bounded scan |dy|<=3;
// exact when m<=16 (side exits >= 81, unscanned rows >= 16). Rare fallback is
// an INLINE cold tail. p0 := 1-p1 (softmax pair, ~1ulp); labf from gt bits.
__global__ __launch_bounds__(256) void fused_loss(
    const float* __restrict__ outputs, const int* __restrict__ labels,
    float* __restrict__ partials)
{
  __shared__ uint64_t W[2][WROWS];   // bit t = window col t (x = x0-8+t)
  __shared__ float wredf[4][5];
  const int tid = threadIdx.x;
  const int wave = tid >> 6, lane = tid & 63;
  const int x0 = blockIdx.x * TW, y0 = blockIdx.y * TH, b = blockIdx.z;
  const int base1 = (b*2 + 1)*PLANE;

  // ---- prefetch epilogue operand (p1 only) first; overlaps staging ----
  const int lx = tid & 31, rg = tid >> 5;    // 8 row-groups of 8 rows
  const int x = x0 + lx;
  const int ybase = y0 + rg*8;
  float p1v[8];
#pragma unroll
  for (int k = 0; k < 8; ++k)
    p1v[k] = outputs[base1 + (ybase + k)*HW + x];

  // ---- stage: 2 masks x 70 rows x 4 ushort chunks (ch 3 = zero pad) ----
  for (int idx = tid; idx < 2*WROWS*4; idx += 256) {
    const int z   = (idx >= WROWS*4) ? 1 : 0;
    const int rem = idx - z*(WROWS*4);
    const int row = rem >> 2, ch = rem & 3;
    const int yy = y0 - YH + row;
    const int xs = x0 - 8 + ch*16;
    uint32_t bits = 0;
    if (ch < 3 && yy >= 0 && yy < HW) {
      const int rb = base1 + yy*HW;
      if (xs >= 0 && xs + 16 <= HW) {
        if (z == 0) {
          const int4* p = (const int4*)(labels + rb + xs);
          const int4 a = p[0], c = p[1], d = p[2], e = p[3];
          const int v[16] = {a.x,a.y,a.z,a.w, c.x,c.y,c.z,c.w,
                             d.x,d.y,d.z,d.w, e.x,e.y,e.z,e.w};
#pragma unroll
          for (int t = 0; t < 16; ++t) if (v[t] <= 0) bits |= (1u << t);
        } else {
          const float4* p = (const float4*)(outputs + rb + xs);
          const float4 a = p[0], c = p[1], d = p[2], e = p[3];
          const float v[16] = {a.x,a.y,a.z,a.w, c.x,c.y,c.z,c.w,
                               d.x,d.y,d.z,d.w, e.x,e.y,e.z,e.w};
#pragma unroll
          for (int t = 0; t < 16; ++t) if (!(v[t] > 0.5f)) bits |= (1u << t);
        }
      } else {
        for (int t = 0; t < 16; ++t) {
          const int xx = xs + t;
          if (xx < 0 || xx >= HW) continue;
          const bool bg = (z == 0) ? (labels[rb + xx] <= 0)
                                   : !(outputs[rb + xx] > 0.5f);
          if (bg) bits |= (1u << t);
        }
      }
    }
    ((unsigned short*)W)[idx] = (unsigned short)bits;  // LE overlay into words
  }
  __syncthreads();

  // ---- branch-free per-pixel EDT: 8 consecutive rows per thread ----
  const int px = 8 + lx, sh = 63 - px;
  const int ry0 = YH + rg*8;                 // window row of first pixel
  float d2sum[8], labf[8];
  uint32_t fbits = 0;                        // fallback flags: bit z*8+k
#pragma unroll
  for (int k = 0; k < 8; ++k) d2sum[k] = 0.0f;
#pragma unroll
  for (int z = 0; z < 2; ++z) {
    int rd2[14];                             // rows ry0-3 .. ry0+10
#pragma unroll
    for (int j = 0; j < 14; ++j) {
      const uint64_t w = W[z][ry0 - YH + j];
      if (z == 0 && j >= 3 && j < 11)        // label>0 <=> gt bit clear
        labf[j-3] = 1.0f - (float)((w >> px) & 1ull);
      const int dL = __builtin_clzll((w << sh) | 1ull);          // empty -> 63
      const int dR = __builtin_ctzll((w >> px) | (1ull << 63));  // empty -> 63
      const int d = min(dL, dR);
      rd2[j] = d*d;
    }
#pragma unroll
    for (int k = 0; k < 8; ++k) {
      int m = rd2[k+3];
      m = min(m, 1 + min(rd2[k+2], rd2[k+4]));
      m = min(m, 4 + min(rd2[k+1], rd2[k+5]));
      m = min(m, 9 + min(rd2[k+0], rd2[k+6]));
      if (__builtin_expect(m > 16, 0)) {     // certificate failed (never)
        fbits |= (1u << (z*8 + k));
      } else {
        d2sum[k] += (float)m;
      }
    }
  }

  // ---- cold inline fallback: exact brute-force for flagged pixels ----
  if (__builtin_expect(fbits != 0, 0)) {
    for (int z = 0; z < 2; ++z) {
      for (int k = 0; k < 8; ++k) {
        if (!(fbits & (1u << (z*8 + k)))) continue;
        const int y = ybase + k;
        int mBest = 0x7fffffff;
        for (int yy = 0; yy < HW; ++yy) {
          const int dy = yy - y, a2 = dy*dy;
          if (a2 >= mBest) continue;
          const int rb = base1 + yy*HW;
          for (int xx = 0; xx < HW; ++xx) {
            const bool bg = (z == 0) ? (labels[rb + xx] <= 0)
                                     : !(outputs[rb + xx] > 0.5f);
            if (bg) {
              const int dx = xx - x, c2 = a2 + dx*dx;
              if (c2 < mBest) mBest = c2;
            }
          }
        }
        d2sum[k] += (mBest == 0x7fffffff) ? INF_F : (float)mBest;
      }
    }
  }

  // ---- fused hd / dice / CE (fp32 partials over 8 px); p0 = 1 - p1 ----
  float s0 = 0, s1 = 0, s2 = 0, s3 = 0, s4 = 0;
#pragma unroll
  for (int k = 0; k < 8; ++k) {
    const float p1  = p1v[k];
    const float p0f = 1.0f - p1;
    const float lf  = labf[k];
    const float dl = p1 - lf;
    s0 = fmaf(dl*dl, d2sum[k], s0);
    s1 = fmaf(p1, lf, s1);
    s2 = fmaf(p1, p1, s2);
    s3 += lf;
    const float mm  = fmaxf(p0f, p1);
    const float lse = mm + __logf(1.0f + __expf(fminf(p0f, p1) - mm));
    s4 += ((lf > 0.5f) ? p1 : p0f) - lse;
  }

  for (int off = 32; off > 0; off >>= 1) {
    s0 += __shfl_down(s0, off, 64);
    s1 += __shfl_down(s1, off, 64);
    s2 += __shfl_down(s2, off, 64);
    s3 += __shfl_down(s3, off, 64);
    s4 += __shfl_down(s4, off, 64);
  }
  if (lane == 0) {
    wredf[wave][0] = s0; wredf[wave][1] = s1; wredf[wave][2] = s2;
    wredf[wave][3] = s3; wredf[wave][4] = s4;
  }
  __syncthreads();
  if (tid < 5) {
    const int bid = (blockIdx.z*GY + blockIdx.y)*GX + blockIdx.x;
    partials[tid*NBLK + bid] =
        wredf[0][tid] + wredf[1][tid] + wredf[2][tid] + wredf[3][tid];
  }
}

// ---------------- Finalize: reduce 1024 block-partials, compute loss --------
__global__ __launch_bounds__(256) void finalize(
    const float* __restrict__ partials, float* __restrict__ out)
{
  __shared__ double wred[4][5];
  const int tid = threadIdx.x;
  double s[5] = {0, 0, 0, 0, 0};
  for (int i = tid; i < NBLK; i += 256) {
#pragma unroll
    for (int q = 0; q < 5; ++q) s[q] += (double)partials[q*NBLK + i];
  }
  for (int off = 32; off > 0; off >>= 1) {
#pragma unroll
    for (int q = 0; q < 5; ++q) s[q] += __shfl_down(s[q], off, 64);
  }
  const int w = tid >> 6;
  if ((tid & 63) == 0) {
#pragma unroll
    for (int q = 0; q < 5; ++q) wred[w][q] = s[q];
  }
  __syncthreads();
  if (tid == 0) {
#pragma unroll
    for (int q = 0; q < 5; ++q) s[q] = wred[0][q] + wred[1][q] + wred[2][q] + wred[3][q];
    const double N = (double)NPIX;
    const double hd   = s[0] / N;
    const double ce   = -(s[4] / N);
    const double dice = 1.0 - (2.0*s[1] + 1e-6) / (s[2] + s[3] + 1e-6);
    out[0] = (float)(ce + dice + 0.5 * hd);   // LAM=1, 1-ALPHA=0.5
  }
}

extern "C" void kernel_launch(void* const* d_in, const int* in_sizes, int n_in,
                              void* d_out, int out_size, void* d_ws, size_t ws_size,
                              hipStream_t stream)
{
  const float* outputs = (const float*)d_in[0];
  const int*   labels  = (const int*)d_in[1];
  float* partials = (float*)d_ws;   // [5][NBLK] floats = 20 KB

  fused_loss<<<dim3(GX, GY, NB), 256, 0, stream>>>(outputs, labels, partials);
  finalize<<<1, 256, 0, stream>>>(partials, (float*)d_out);
}